// Round 11
// baseline (173.680 us; speedup 1.0000x reference)
//
#include <hip/hip_runtime.h>
#include <stdint.h>
#include <stddef.h>

typedef short bfrag __attribute__((ext_vector_type(8)));
typedef float f32x4 __attribute__((ext_vector_type(4)));
typedef float f32x4u __attribute__((ext_vector_type(4), aligned(4)));  // rows are only 4B-aligned

#define NSEQ 7
// feats packed in MFMA A-fragment order: [btile(1024)][step(18)][lane(64)][j(8)] bf16
// value = feat[btile*16 + (lane&15)][k], k = step*32 + (lane>>4)*8 + j

__constant__ int c_ks[5] = {1, 3, 5, 7, 9};

// per-ksize active MFMA K-steps (B is exactly zero outside): s in [lo, lo+n)
#define SLO0 3
#define SLO1 2
#define SLO2 1
#define SLO3 0
#define SLO4 0
#define SN0 1
#define SN1 3
#define SN2 5
#define SN3 6
#define SN4 7

// LDS layout (halfwords): staging [32][SHW] bf16 (SHW padded to ==24 mod 64);
// max SHW = 664 (L=18) -> 21248 hw staging. pmax int[32][84]: stride 84 so the
// 4-quad atomicMax merge is a 2-way bank split not 4-way (336q == 16q mod 32;
// conflicts 3.6M->2.48M measured r9). Total 53248 B -> 3 blocks/CU.
// Block structure = r4's (32 samples, 3584 blocks): r6 explicit pipeline -13%,
// r7 2-chunk blocks -24%, r8 sparse-zero -11% all regressed — inter-block phase
// overlap at 3 blocks/CU is the pipeline; don't lengthen the serial path.
#define STAGE_MAX_HW 21248
#define PMAX_STRIDE 84
#define XL_HW (STAGE_MAX_HW + 32 * PMAX_STRIDE * 2)   // 26624 hw = 53248 B

static __device__ __forceinline__ unsigned short f2bf(float f) {
  unsigned int u = __float_as_uint(f);
  u += 0x7FFFu + ((u >> 16) & 1u);   // RNE
  return (unsigned short)(u >> 16);
}

// ---------------- prep: pack conv weights + lin1 into B-fragment layout ----------
struct PrepArgs {
  const float* Wk[5];
  const float* lin1_w;
  bfrag* Wpack;
  bfrag* lin1pack;
};

__global__ __launch_bounds__(256) void prep_kernel(PrepArgs a) {
  int tid = blockIdx.x * 256 + threadIdx.x;
  const int NW = NSEQ * 5 * 7 * 64;
  if (tid < NW) {
    int lane = tid & 63, rest = tid >> 6;
    int step = rest % 7, nt = (rest / 7) % 5, seq = rest / 35;
    int quad = lane >> 4, f = lane & 15;
    int ks = c_ks[nt], off = (9 - ks) >> 1;
    const float* W = a.Wk[nt];
    bfrag s;
#pragma unroll
    for (int j = 0; j < 8; ++j) {
      int k = step * 32 + quad * 8 + j;
      int t = k / 24, c = k % 24;
      int tap = t - off;
      float val = 0.f;
      if (c < 20 && tap >= 0 && tap < ks)
        val = W[((seq * 16 + f) * 20 + c) * ks + tap] * 0.2f;  // fold /5
      s[j] = (short)f2bf(val);
    }
    a.Wpack[tid] = s;
  } else if (tid < NW + 4 * 18 * 64) {
    int t2 = tid - NW;
    int lane = t2 & 63, rest = t2 >> 6;
    int step = rest % 18, nt = rest / 18;
    int quad = lane >> 4, col = lane & 15;
    int n = nt * 16 + col;
    bfrag s;
#pragma unroll
    for (int j = 0; j < 8; ++j) {
      int k = step * 32 + quad * 8 + j;
      float val = (k < 560) ? a.lin1_w[n * 560 + k] : 0.f;  // zero rows k>=560 make feats pad inert
      s[j] = (short)f2bf(val);
    }
    a.lin1pack[t2] = s;
  }
}

// ---------------- conv+relu+gmax: sample-tile MFMA, register max over positions ----
struct ConvArgs {
  const float* x[NSEQ];
  const bfrag* Wpack;
  unsigned short* feats;   // packed A-frag layout, see top
};

// Block = 32 samples (2 M-tiles of 16). Staging is two-phase (issue all loads,
// one drain, cvt+write). Compute uses a SLIDING A-WINDOW: a wave's next
// position l+4 is 96 hw = exactly 3 K-steps ahead, so Af_{l+4}[s] = Af_l[s+3]
// for s=0..3 — rotate 4 named regs, ds_read only s=4,5,6 (7 -> 3 b128 reads
// per position after the first; 4 of 5 MFMA groups start on rotated regs
// without waiting on LDS). Named A0..A6: static indices only (scratch rule).
template <int L>
__device__ __forceinline__ void conv_body(unsigned short* xl, const ConvArgs& a,
                                          const int seq, const int b0) {
  constexpr int Pv = L + 9;                 // 4 leading pad + L + 5 trailing pad
  constexpr int SHW0 = Pv * 24;
  constexpr int SHW = SHW0 + ((24 - (SHW0 & 63)) & 63);   // == 24 mod 64 halfwords
  constexpr int STAGE_HW = 32 * SHW;
  constexpr int NC = (L + 3) / 4;           // overlapping float4 chunks per row
  int* pmax = (int*)(xl + STAGE_MAX_HW);
  const int tid = threadIdx.x;
  const float* xg = a.x[seq];

  // zero staging slab (dense, coalesced uint4 — r8's sparse variant regressed)
  // and pmax (32*84 ints = 672 uint4)
  for (int i = tid; i < STAGE_HW / 8; i += 256) ((uint4*)xl)[i] = uint4{0, 0, 0, 0};
  for (int i = tid; i < 672; i += 256) ((uint4*)pmax)[i] = uint4{0, 0, 0, 0};
  __syncthreads();

  // stage x -> bf16 [b][pos=xi+4][c]: 320 jobs = (sample, channel-pair);
  // rows 2cp/2cp+1 contiguous in global.
  // phase A: issue ALL loads (<=2 jobs x NC chunks x 2 rows), hold in regs
  f32x4u ra[2][NC], rb[2][NC];
#pragma unroll
  for (int t = 0; t < 2; ++t) {
    if (t == 0 || tid < 64) {               // 320 - 256 = 64 second jobs
      int j = tid + t * 256;
      int b = j / 10, cp = j - (j / 10) * 10;
      const float* rowA = xg + ((size_t)(b0 + b) * 20 + 2 * cp) * L;
#pragma unroll
      for (int ci = 0; ci < NC; ++ci) {
        int xi0 = (4 * ci > L - 4) ? (L - 4) : 4 * ci;   // overlapping tail chunk
        ra[t][ci] = *(const f32x4u*)(rowA + xi0);
        rb[t][ci] = *(const f32x4u*)(rowA + L + xi0);
      }
    }
  }
  // phase B: packed cvt + b32 LDS writes (one latency drain for all loads)
#pragma unroll
  for (int t = 0; t < 2; ++t) {
    if (t == 0 || tid < 64) {
      int j = tid + t * 256;
      int b = j / 10, cp = j - (j / 10) * 10;
      unsigned short* dstb = xl + b * SHW + 4 * 24 + 2 * cp;
#pragma unroll
      for (int ci = 0; ci < NC; ++ci) {
        int xi0 = (4 * ci > L - 4) ? (L - 4) : 4 * ci;
#pragma unroll
        for (int jj = 0; jj < 4; ++jj) {
          unsigned int pk;
          asm("v_cvt_pk_bf16_f32 %0, %1, %2" : "=v"(pk) : "v"(ra[t][ci][jj]), "v"(rb[t][ci][jj]));
          *(unsigned int*)(dstb + (xi0 + jj) * 24) = pk;   // 4B-aligned: SHW even, 2cp even
        }
      }
    }
  }

  const int wave = tid >> 6, lane = tid & 63, quad = lane >> 4, m = lane & 15;

  // preload the 22 non-zero B fragments for this seq (after the write loop so
  // the held-register peak stays bounded; latency hides under the barrier)
  const bfrag* wp = a.Wpack + (size_t)(seq * 5 * 7) * 64 + lane;
  bfrag Bf[22];
  {
    int bi = 0;
#pragma unroll
    for (int i = 0; i < SN0; ++i) Bf[bi++] = wp[(0 * 7 + SLO0 + i) * 64];
#pragma unroll
    for (int i = 0; i < SN1; ++i) Bf[bi++] = wp[(1 * 7 + SLO1 + i) * 64];
#pragma unroll
    for (int i = 0; i < SN2; ++i) Bf[bi++] = wp[(2 * 7 + SLO2 + i) * 64];
#pragma unroll
    for (int i = 0; i < SN3; ++i) Bf[bi++] = wp[(3 * 7 + SLO3 + i) * 64];
#pragma unroll
    for (int i = 0; i < SN4; ++i) Bf[bi++] = wp[(4 * 7 + SLO4 + i) * 64];
  }
  // Bf base offsets per nt: {0, 1, 4, 9, 15}

  __syncthreads();   // chunk staged

  // compute the two 16-sample M-tiles (positions round-robin over waves)
#pragma unroll
  for (int mt = 0; mt < 2; ++mt) {
    f32x4 vmax[5];
#pragma unroll
    for (int g = 0; g < 5; ++g) vmax[g] = f32x4{0.f, 0.f, 0.f, 0.f};  // relu folded

    const unsigned short* abase = &xl[(mt * 16 + m) * SHW + quad * 8];
    int l = wave;                      // wave < 4 <= L: all waves enter, uniform
    bfrag A0, A1, A2, A3, A4, A5, A6;
    {
      const unsigned short* ar = abase + l * 24;
      A0 = *(const bfrag*)(ar + 0);
      A1 = *(const bfrag*)(ar + 32);
      A2 = *(const bfrag*)(ar + 64);
      A3 = *(const bfrag*)(ar + 96);
      A4 = *(const bfrag*)(ar + 128);
      A5 = *(const bfrag*)(ar + 160);
      A6 = *(const bfrag*)(ar + 192);
    }
    while (true) {
      f32x4 acc[5];
#pragma unroll
      for (int g = 0; g < 5; ++g) acc[g] = f32x4{0.f, 0.f, 0.f, 0.f};
#define MF(g, bi, A) acc[g] = __builtin_amdgcn_mfma_f32_16x16x32_bf16(A, Bf[bi], acc[g], 0, 0, 0)
      // s-major order (same schedule shape as before); group->Bf base {0,1,4,9,15}
      MF(3, 9, A0);  MF(4, 15, A0);                                  // s=0
      MF(2, 4, A1);  MF(3, 10, A1); MF(4, 16, A1);                   // s=1
      MF(1, 1, A2);  MF(2, 5, A2);  MF(3, 11, A2); MF(4, 17, A2);    // s=2
      MF(0, 0, A3);  MF(1, 2, A3);  MF(2, 6, A3);  MF(3, 12, A3); MF(4, 18, A3);  // s=3
      MF(1, 3, A4);  MF(2, 7, A4);  MF(3, 13, A4); MF(4, 19, A4);    // s=4
      MF(2, 8, A5);  MF(3, 14, A5); MF(4, 20, A5);                   // s=5
      MF(4, 21, A6);                                                 // s=6
#undef MF
#pragma unroll
      for (int g = 0; g < 5; ++g) {
#pragma unroll
        for (int r4 = 0; r4 < 4; ++r4) vmax[g][r4] = fmaxf(vmax[g][r4], acc[g][r4]);
      }
      l += 4;
      if (l >= L) break;
      // slide the window: 96 hw = 3 steps; only s=4,5,6 are new
      A0 = A3; A1 = A4; A2 = A5; A3 = A6;
      const unsigned short* ar = abase + l * 24;
      A4 = *(const bfrag*)(ar + 128);
      A5 = *(const bfrag*)(ar + 160);
      A6 = *(const bfrag*)(ar + 192);
    }
    // merge waves' running maxima: C row = quad*4+r4 = sample, col m = filter
#pragma unroll
    for (int g = 0; g < 5; ++g) {
#pragma unroll
      for (int r4 = 0; r4 < 4; ++r4)
        atomicMax(&pmax[(mt * 16 + quad * 4 + r4) * PMAX_STRIDE + g * 16 + m],
                  __float_as_int(vmax[g][r4]));
    }
  }
  __syncthreads();   // pmax complete

  // store: 32 samples x 10 chunks of 8 consecutive k -> one 16B store each
  for (int r = tid; r < 320; r += 256) {
    int s = r / 10, c = r - (r / 10) * 10;
    int k0 = seq * 80 + c * 8;               // multiple of 8
    bfrag outv;
#pragma unroll
    for (int j = 0; j < 8; ++j)
      outv[j] = (short)f2bf(__int_as_float(pmax[s * PMAX_STRIDE + c * 8 + j]));
    int step = k0 >> 5, q = (k0 >> 3) & 3;
    int b = b0 + s;
    *(bfrag*)(a.feats + ((size_t)(b >> 4) * 18 + step) * 512 + (size_t)(q * 16 + (b & 15)) * 8) = outv;
  }
}

__global__ __launch_bounds__(256, 3) void conv_kernel(ConvArgs a) {
  __shared__ __align__(16) unsigned short xl[XL_HW];   // 53248 B -> 3 blocks/CU
  const int bid = blockIdx.x;
  // grouped + LPT-ordered: 512 contiguous blocks per seq, longest L first.
  const int grp = bid >> 9, b0 = (bid & 511) * 32;
  switch (grp) {
    case 0: conv_body<18>(xl, a, 6, b0); break;   // L=18
    case 1: conv_body<16>(xl, a, 3, b0); break;   // L=16
    case 2: conv_body<12>(xl, a, 0, b0); break;   // L=12
    case 3: conv_body< 8>(xl, a, 2, b0); break;   // L=8
    case 4: conv_body< 7>(xl, a, 1, b0); break;   // L=7
    case 5: conv_body< 7>(xl, a, 5, b0); break;   // L=7
    default: conv_body< 6>(xl, a, 4, b0); break;  // L=6
  }
}

// ---------------- MLP: feats(packed) -> sigmoid(@lin1^T+b1) -> @lin2^T+b2 ----------------
// 32 samples/block (2 feats btiles): halves the per-block 73.7 KB lin1pack
// re-read and gives each wave two independent MFMA chains (r10: total -4.3us).
struct MlpArgs {
  const bfrag* feats;      // packed A-frag layout
  const bfrag* lin1pack;
  const float* lin1_b;
  const float* lin2_w;
  const float* lin2_b;
  float* out;
};

__global__ __launch_bounds__(256, 4) void mlp_kernel(MlpArgs a) {
  __shared__ float h[32 * 68];
  __shared__ float w2[64];
  const int tid = threadIdx.x;
  const int b0 = blockIdx.x * 32;
  if (tid < 64) w2[tid] = a.lin2_w[tid];
  const int wave = tid >> 6, lane = tid & 63, quad = lane >> 4, m = lane & 15;
  const int nt = wave;                     // one n-tile per wave
  bfrag Bf[18];
#pragma unroll
  for (int s = 0; s < 18; ++s) Bf[s] = a.lin1pack[(nt * 18 + s) * 64 + lane];
  const bfrag* ap0 = a.feats + (size_t)(2 * blockIdx.x) * 18 * 64 + lane;  // btile 2i
  const bfrag* ap1 = ap0 + 18 * 64;                                        // btile 2i+1
  f32x4 acc0 = {0.f, 0.f, 0.f, 0.f}, acc1 = {0.f, 0.f, 0.f, 0.f};
#pragma unroll
  for (int s = 0; s < 18; ++s) {
    acc0 = __builtin_amdgcn_mfma_f32_16x16x32_bf16(ap0[s * 64], Bf[s], acc0, 0, 0, 0);
    acc1 = __builtin_amdgcn_mfma_f32_16x16x32_bf16(ap1[s * 64], Bf[s], acc1, 0, 0, 0);
  }
  int n = nt * 16 + m;
  float bias = a.lin1_b[n];
#pragma unroll
  for (int r = 0; r < 4; ++r) {
    float p0 = acc0[r] + bias, p1 = acc1[r] + bias;
    h[(quad * 4 + r) * 68 + n] = 1.f / (1.f + __expf(-p0));
    h[(16 + quad * 4 + r) * 68 + n] = 1.f / (1.f + __expf(-p1));
  }
  __syncthreads();
  int q = tid & 15;                        // 16 threads per sample, 4 h each
#pragma unroll
  for (int half = 0; half < 2; ++half) {
    int bl = (tid >> 4) + half * 16;
    const float* hr = &h[bl * 68 + q * 4];
    float s = hr[0] * w2[q * 4] + hr[1] * w2[q * 4 + 1] + hr[2] * w2[q * 4 + 2] + hr[3] * w2[q * 4 + 3];
    s += __shfl_xor(s, 1);
    s += __shfl_xor(s, 2);
    s += __shfl_xor(s, 4);
    s += __shfl_xor(s, 8);
    if (q == 0) a.out[b0 + bl] = s + a.lin2_b[0];
  }
}

// ---------------- launch ----------------
extern "C" void kernel_launch(void* const* d_in, const int* in_sizes, int n_in,
                              void* d_out, int out_size, void* d_ws, size_t ws_size,
                              hipStream_t stream) {
  (void)in_sizes; (void)n_in; (void)out_size; (void)ws_size;
  char* ws = (char*)d_ws;
  bfrag* Wpack = (bfrag*)(ws + 0);                 // 15680*16 = 250,880 B
  bfrag* lin1pack = (bfrag*)(ws + 262144);         // 4608*16  =  73,728 B
  unsigned short* feats = (unsigned short*)(ws + 393216);  // 1024*18*64*16 = 18.87 MB

  PrepArgs pa;
  for (int j = 0; j < 5; ++j) pa.Wk[j] = (const float*)d_in[7 + j];
  pa.lin1_w = (const float*)d_in[12];
  pa.Wpack = Wpack;
  pa.lin1pack = lin1pack;
  prep_kernel<<<80, 256, 0, stream>>>(pa);

  ConvArgs ca;
  for (int i = 0; i < NSEQ; ++i) ca.x[i] = (const float*)d_in[i];
  ca.Wpack = Wpack;
  ca.feats = feats;
  // 3584 blocks: 512 per seq (32 samples each), grouped by seq, longest-L first
  conv_kernel<<<3584, 256, 0, stream>>>(ca);

  MlpArgs ma;
  ma.feats = (const bfrag*)feats;
  ma.lin1pack = lin1pack;
  ma.lin1_b = (const float*)d_in[13];
  ma.lin2_w = (const float*)d_in[14];
  ma.lin2_b = (const float*)d_in[15];
  ma.out = (float*)d_out;
  mlp_kernel<<<512, 256, 0, stream>>>(ma);
}

// Round 13
// 172.340 us; speedup vs baseline: 1.0078x; 1.0078x over previous
//
#include <hip/hip_runtime.h>
#include <stdint.h>
#include <stddef.h>

typedef short bfrag __attribute__((ext_vector_type(8)));
typedef float f32x4 __attribute__((ext_vector_type(4)));
typedef float f32x4u __attribute__((ext_vector_type(4), aligned(4)));  // rows are only 4B-aligned

#define NSEQ 7
// feats packed in MFMA A-fragment order: [btile(1024)][step(18)][lane(64)][j(8)] bf16
// value = feat[btile*16 + (lane&15)][k], k = step*32 + (lane>>4)*8 + j

__constant__ int c_ks[5] = {1, 3, 5, 7, 9};

// per-ksize active MFMA K-steps (B is exactly zero outside): s in [lo, lo+n)
#define SLO0 3
#define SLO1 2
#define SLO2 1
#define SLO3 0
#define SLO4 0
#define SN0 1
#define SN1 3
#define SN2 5
#define SN3 6
#define SN4 7

// LDS layout (halfwords): staging [32][SHW] bf16 (SHW padded to ==24 mod 64);
// max SHW = 664 (L=18) -> 21248 hw staging. pmax int[32][84]: stride 84 so the
// 4-quad atomicMax merge is a 2-way bank split not 4-way (336q == 16q mod 32;
// conflicts 3.6M->2.48M measured r9). Total 53248 B -> 3 blocks/CU.
// Block structure = r4's (32 samples, 3584 blocks). SETTLED by measurement:
//   r6 explicit intra-block pipeline  -13%
//   r7 2-chunk (64-sample) blocks     -24%
//   r8 sparse pad-only zeroing        -11%
//   r11 sliding A-window (7->3 reads) -3.5% (serialized the load schedule)
// Inter-block phase overlap at 3 blocks/CU IS the pipeline; per-position loads
// must stay independent so the compiler can batch-issue them under MFMAs.
#define STAGE_MAX_HW 21248
#define PMAX_STRIDE 84
#define XL_HW (STAGE_MAX_HW + 32 * PMAX_STRIDE * 2)   // 26624 hw = 53248 B

static __device__ __forceinline__ unsigned short f2bf(float f) {
  unsigned int u = __float_as_uint(f);
  u += 0x7FFFu + ((u >> 16) & 1u);   // RNE
  return (unsigned short)(u >> 16);
}

// ---------------- prep: pack conv weights + lin1 into B-fragment layout ----------
struct PrepArgs {
  const float* Wk[5];
  const float* lin1_w;
  bfrag* Wpack;
  bfrag* lin1pack;
};

__global__ __launch_bounds__(256) void prep_kernel(PrepArgs a) {
  int tid = blockIdx.x * 256 + threadIdx.x;
  const int NW = NSEQ * 5 * 7 * 64;
  if (tid < NW) {
    int lane = tid & 63, rest = tid >> 6;
    int step = rest % 7, nt = (rest / 7) % 5, seq = rest / 35;
    int quad = lane >> 4, f = lane & 15;
    int ks = c_ks[nt], off = (9 - ks) >> 1;
    const float* W = a.Wk[nt];
    bfrag s;
#pragma unroll
    for (int j = 0; j < 8; ++j) {
      int k = step * 32 + quad * 8 + j;
      int t = k / 24, c = k % 24;
      int tap = t - off;
      float val = 0.f;
      if (c < 20 && tap >= 0 && tap < ks)
        val = W[((seq * 16 + f) * 20 + c) * ks + tap] * 0.2f;  // fold /5
      s[j] = (short)f2bf(val);
    }
    a.Wpack[tid] = s;
  } else if (tid < NW + 4 * 18 * 64) {
    int t2 = tid - NW;
    int lane = t2 & 63, rest = t2 >> 6;
    int step = rest % 18, nt = rest / 18;
    int quad = lane >> 4, col = lane & 15;
    int n = nt * 16 + col;
    bfrag s;
#pragma unroll
    for (int j = 0; j < 8; ++j) {
      int k = step * 32 + quad * 8 + j;
      float val = (k < 560) ? a.lin1_w[n * 560 + k] : 0.f;  // zero rows k>=560 make feats pad inert
      s[j] = (short)f2bf(val);
    }
    a.lin1pack[t2] = s;
  }
}

// ---------------- conv+relu+gmax: sample-tile MFMA, register max over positions ----
struct ConvArgs {
  const float* x[NSEQ];
  const bfrag* Wpack;
  unsigned short* feats;   // packed A-frag layout, see top
};

template <int SLO, int SN>
static __device__ __forceinline__ void mfma_group(f32x4& acc, int s, const bfrag& Af,
                                                  const bfrag* BfBase) {
  if (s >= SLO && s < SLO + SN)
    acc = __builtin_amdgcn_mfma_f32_16x16x32_bf16(Af, BfBase[s - SLO], acc, 0, 0, 0);
}

// One 16-sample MFMA tile over all 5 filter groups. arow = A base (includes quad*8).
// 7 INDEPENDENT b128 reads per position — do not introduce cross-position register
// reuse (r11: serializing these cost 3.5%).
static __device__ __forceinline__ void tile_mfma(const unsigned short* arow, const bfrag* Bf,
                                                 f32x4 acc[5]) {
#pragma unroll
  for (int s = 0; s < 7; ++s) {
    bfrag Af = *(const bfrag*)(arow + s * 32);
    mfma_group<SLO0, SN0>(acc[0], s, Af, Bf + 0);
    mfma_group<SLO1, SN1>(acc[1], s, Af, Bf + 1);
    mfma_group<SLO2, SN2>(acc[2], s, Af, Bf + 4);
    mfma_group<SLO3, SN3>(acc[3], s, Af, Bf + 9);
    acc[4] = __builtin_amdgcn_mfma_f32_16x16x32_bf16(Af, Bf[15 + s], acc[4], 0, 0, 0);
  }
}

// Block = 32 samples (2 M-tiles of 16). Staging is two-phase (issue all loads,
// one drain, cvt+write). Live peak ~110 VGPR < 168 (3-waves/EU cap; (256,4)=128
// caused scratch spills in r2).
template <int L>
__device__ __forceinline__ void conv_body(unsigned short* xl, const ConvArgs& a,
                                          const int seq, const int b0) {
  constexpr int Pv = L + 9;                 // 4 leading pad + L + 5 trailing pad
  constexpr int SHW0 = Pv * 24;
  constexpr int SHW = SHW0 + ((24 - (SHW0 & 63)) & 63);   // == 24 mod 64 halfwords
  constexpr int STAGE_HW = 32 * SHW;
  constexpr int NC = (L + 3) / 4;           // overlapping float4 chunks per row
  int* pmax = (int*)(xl + STAGE_MAX_HW);
  const int tid = threadIdx.x;
  const float* xg = a.x[seq];

  // zero staging slab (dense, coalesced uint4 — r8's sparse variant regressed)
  // and pmax (32*84 ints = 672 uint4)
  for (int i = tid; i < STAGE_HW / 8; i += 256) ((uint4*)xl)[i] = uint4{0, 0, 0, 0};
  for (int i = tid; i < 672; i += 256) ((uint4*)pmax)[i] = uint4{0, 0, 0, 0};
  __syncthreads();

  // stage x -> bf16 [b][pos=xi+4][c]: 320 jobs = (sample, channel-pair);
  // rows 2cp/2cp+1 contiguous in global.
  // phase A: issue ALL loads (<=2 jobs x NC chunks x 2 rows), hold in regs
  f32x4u ra[2][NC], rb[2][NC];
#pragma unroll
  for (int t = 0; t < 2; ++t) {
    if (t == 0 || tid < 64) {               // 320 - 256 = 64 second jobs
      int j = tid + t * 256;
      int b = j / 10, cp = j - (j / 10) * 10;
      const float* rowA = xg + ((size_t)(b0 + b) * 20 + 2 * cp) * L;
#pragma unroll
      for (int ci = 0; ci < NC; ++ci) {
        int xi0 = (4 * ci > L - 4) ? (L - 4) : 4 * ci;   // overlapping tail chunk
        ra[t][ci] = *(const f32x4u*)(rowA + xi0);
        rb[t][ci] = *(const f32x4u*)(rowA + L + xi0);
      }
    }
  }
  // phase B: packed cvt + b32 LDS writes (one latency drain for all loads)
#pragma unroll
  for (int t = 0; t < 2; ++t) {
    if (t == 0 || tid < 64) {
      int j = tid + t * 256;
      int b = j / 10, cp = j - (j / 10) * 10;
      unsigned short* dstb = xl + b * SHW + 4 * 24 + 2 * cp;
#pragma unroll
      for (int ci = 0; ci < NC; ++ci) {
        int xi0 = (4 * ci > L - 4) ? (L - 4) : 4 * ci;
#pragma unroll
        for (int jj = 0; jj < 4; ++jj) {
          unsigned int pk;
          asm("v_cvt_pk_bf16_f32 %0, %1, %2" : "=v"(pk) : "v"(ra[t][ci][jj]), "v"(rb[t][ci][jj]));
          *(unsigned int*)(dstb + (xi0 + jj) * 24) = pk;   // 4B-aligned: SHW even, 2cp even
        }
      }
    }
  }

  const int wave = tid >> 6, lane = tid & 63, quad = lane >> 4, m = lane & 15;

  // preload the 22 non-zero B fragments for this seq (after the write loop so
  // the held-register peak stays bounded; latency hides under the barrier)
  const bfrag* wp = a.Wpack + (size_t)(seq * 5 * 7) * 64 + lane;
  bfrag Bf[22];
  {
    int bi = 0;
#pragma unroll
    for (int i = 0; i < SN0; ++i) Bf[bi++] = wp[(0 * 7 + SLO0 + i) * 64];
#pragma unroll
    for (int i = 0; i < SN1; ++i) Bf[bi++] = wp[(1 * 7 + SLO1 + i) * 64];
#pragma unroll
    for (int i = 0; i < SN2; ++i) Bf[bi++] = wp[(2 * 7 + SLO2 + i) * 64];
#pragma unroll
    for (int i = 0; i < SN3; ++i) Bf[bi++] = wp[(3 * 7 + SLO3 + i) * 64];
#pragma unroll
    for (int i = 0; i < SN4; ++i) Bf[bi++] = wp[(4 * 7 + SLO4 + i) * 64];
  }
  // Bf base offsets per nt: {0, 1, 4, 9, 15}

  __syncthreads();   // chunk staged

  // compute the two 16-sample M-tiles (positions round-robin over waves)
#pragma unroll
  for (int mt = 0; mt < 2; ++mt) {
    f32x4 vmax[5];
#pragma unroll
    for (int g = 0; g < 5; ++g) vmax[g] = f32x4{0.f, 0.f, 0.f, 0.f};  // relu folded
    for (int l = wave; l < L; l += 4) {
      const unsigned short* arow = &xl[(mt * 16 + m) * SHW + l * 24 + quad * 8];
      f32x4 acc[5];
#pragma unroll
      for (int g = 0; g < 5; ++g) acc[g] = f32x4{0.f, 0.f, 0.f, 0.f};
      tile_mfma(arow, Bf, acc);
#pragma unroll
      for (int g = 0; g < 5; ++g) {
#pragma unroll
        for (int r4 = 0; r4 < 4; ++r4) vmax[g][r4] = fmaxf(vmax[g][r4], acc[g][r4]);
      }
    }
    // merge waves' running maxima: C row = quad*4+r4 = sample, col m = filter
#pragma unroll
    for (int g = 0; g < 5; ++g) {
#pragma unroll
      for (int r4 = 0; r4 < 4; ++r4)
        atomicMax(&pmax[(mt * 16 + quad * 4 + r4) * PMAX_STRIDE + g * 16 + m],
                  __float_as_int(vmax[g][r4]));
    }
  }
  __syncthreads();   // pmax complete

  // store: 32 samples x 10 chunks of 8 consecutive k -> one 16B store each
  for (int r = tid; r < 320; r += 256) {
    int s = r / 10, c = r - (r / 10) * 10;
    int k0 = seq * 80 + c * 8;               // multiple of 8
    bfrag outv;
#pragma unroll
    for (int j = 0; j < 8; ++j)
      outv[j] = (short)f2bf(__int_as_float(pmax[s * PMAX_STRIDE + c * 8 + j]));
    int step = k0 >> 5, q = (k0 >> 3) & 3;
    int b = b0 + s;
    *(bfrag*)(a.feats + ((size_t)(b >> 4) * 18 + step) * 512 + (size_t)(q * 16 + (b & 15)) * 8) = outv;
  }
}

__global__ __launch_bounds__(256, 3) void conv_kernel(ConvArgs a) {
  __shared__ __align__(16) unsigned short xl[XL_HW];   // 53248 B -> 3 blocks/CU
  const int bid = blockIdx.x;
  // grouped + LPT-ordered: 512 contiguous blocks per seq, longest L first.
  const int grp = bid >> 9, b0 = (bid & 511) * 32;
  switch (grp) {
    case 0: conv_body<18>(xl, a, 6, b0); break;   // L=18
    case 1: conv_body<16>(xl, a, 3, b0); break;   // L=16
    case 2: conv_body<12>(xl, a, 0, b0); break;   // L=12
    case 3: conv_body< 8>(xl, a, 2, b0); break;   // L=8
    case 4: conv_body< 7>(xl, a, 1, b0); break;   // L=7
    case 5: conv_body< 7>(xl, a, 5, b0); break;   // L=7
    default: conv_body< 6>(xl, a, 4, b0); break;  // L=6
  }
}

// ---------------- MLP: feats(packed) -> sigmoid(@lin1^T+b1) -> @lin2^T+b2 ----------------
// 32 samples/block (2 feats btiles): halves the per-block 73.7 KB lin1pack
// re-read and gives each wave two independent MFMA chains (r10: total -4.3us).
struct MlpArgs {
  const bfrag* feats;      // packed A-frag layout
  const bfrag* lin1pack;
  const float* lin1_b;
  const float* lin2_w;
  const float* lin2_b;
  float* out;
};

__global__ __launch_bounds__(256, 4) void mlp_kernel(MlpArgs a) {
  __shared__ float h[32 * 68];
  __shared__ float w2[64];
  const int tid = threadIdx.x;
  const int b0 = blockIdx.x * 32;
  if (tid < 64) w2[tid] = a.lin2_w[tid];
  const int wave = tid >> 6, lane = tid & 63, quad = lane >> 4, m = lane & 15;
  const int nt = wave;                     // one n-tile per wave
  bfrag Bf[18];
#pragma unroll
  for (int s = 0; s < 18; ++s) Bf[s] = a.lin1pack[(nt * 18 + s) * 64 + lane];
  const bfrag* ap0 = a.feats + (size_t)(2 * blockIdx.x) * 18 * 64 + lane;  // btile 2i
  const bfrag* ap1 = ap0 + 18 * 64;                                        // btile 2i+1
  f32x4 acc0 = {0.f, 0.f, 0.f, 0.f}, acc1 = {0.f, 0.f, 0.f, 0.f};
#pragma unroll
  for (int s = 0; s < 18; ++s) {
    acc0 = __builtin_amdgcn_mfma_f32_16x16x32_bf16(ap0[s * 64], Bf[s], acc0, 0, 0, 0);
    acc1 = __builtin_amdgcn_mfma_f32_16x16x32_bf16(ap1[s * 64], Bf[s], acc1, 0, 0, 0);
  }
  int n = nt * 16 + m;
  float bias = a.lin1_b[n];
#pragma unroll
  for (int r = 0; r < 4; ++r) {
    float p0 = acc0[r] + bias, p1 = acc1[r] + bias;
    h[(quad * 4 + r) * 68 + n] = 1.f / (1.f + __expf(-p0));
    h[(16 + quad * 4 + r) * 68 + n] = 1.f / (1.f + __expf(-p1));
  }
  __syncthreads();
  int q = tid & 15;                        // 16 threads per sample, 4 h each
#pragma unroll
  for (int half = 0; half < 2; ++half) {
    int bl = (tid >> 4) + half * 16;
    const float* hr = &h[bl * 68 + q * 4];
    float s = hr[0] * w2[q * 4] + hr[1] * w2[q * 4 + 1] + hr[2] * w2[q * 4 + 2] + hr[3] * w2[q * 4 + 3];
    s += __shfl_xor(s, 1);
    s += __shfl_xor(s, 2);
    s += __shfl_xor(s, 4);
    s += __shfl_xor(s, 8);
    if (q == 0) a.out[b0 + bl] = s + a.lin2_b[0];
  }
}

// ---------------- launch ----------------
extern "C" void kernel_launch(void* const* d_in, const int* in_sizes, int n_in,
                              void* d_out, int out_size, void* d_ws, size_t ws_size,
                              hipStream_t stream) {
  (void)in_sizes; (void)n_in; (void)out_size; (void)ws_size;
  char* ws = (char*)d_ws;
  bfrag* Wpack = (bfrag*)(ws + 0);                 // 15680*16 = 250,880 B
  bfrag* lin1pack = (bfrag*)(ws + 262144);         // 4608*16  =  73,728 B
  unsigned short* feats = (unsigned short*)(ws + 393216);  // 1024*18*64*16 = 18.87 MB

  PrepArgs pa;
  for (int j = 0; j < 5; ++j) pa.Wk[j] = (const float*)d_in[7 + j];
  pa.lin1_w = (const float*)d_in[12];
  pa.Wpack = Wpack;
  pa.lin1pack = lin1pack;
  prep_kernel<<<80, 256, 0, stream>>>(pa);

  ConvArgs ca;
  for (int i = 0; i < NSEQ; ++i) ca.x[i] = (const float*)d_in[i];
  ca.Wpack = Wpack;
  ca.feats = feats;
  // 3584 blocks: 512 per seq (32 samples each), grouped by seq, longest-L first
  conv_kernel<<<3584, 256, 0, stream>>>(ca);

  MlpArgs ma;
  ma.feats = (const bfrag*)feats;
  ma.lin1pack = lin1pack;
  ma.lin1_b = (const float*)d_in[13];
  ma.lin2_w = (const float*)d_in[14];
  ma.lin2_b = (const float*)d_in[15];
  ma.out = (float*)d_out;
  mlp_kernel<<<512, 256, 0, stream>>>(ma);
}